// Round 2
// baseline (305.197 us; speedup 1.0000x reference)
//
#include <hip/hip_runtime.h>
#include <math.h>

#define DIM 128
#define TEMP_INV 10.0f
#define LOG2E 1.4426950408889634f
#define QSCALE 20.0f
#define NCLASS 16              // bitmap capacity (problem has 10 classes)
// sim*10*log2e = dint * (10*log2e/400)
#define C0 (TEMP_INV * LOG2E / (QSCALE * QSCALE))
#define ONES 0x11111111u
#define CAP 80                 // records per bin (lambda=40, P(ovf)~1e-8/bin)
#define OVF_MAX 4096           // overflow list capacity (expected use: ~0)

#if __has_builtin(__builtin_amdgcn_udot8)
#define UDOT8(a, b, c) __builtin_amdgcn_udot8((a), (b), (c), false)
#else
static __device__ __forceinline__ unsigned udot8_sw(unsigned a, unsigned b, unsigned c) {
#pragma unroll
    for (int i = 0; i < 8; ++i)
        c += ((a >> (4 * i)) & 15u) * ((b >> (4 * i)) & 15u);
    return c;
}
#define UDOT8(a, b, c) udot8_sw((a), (b), (c))
#endif

// ---------------- int4 fast path ----------------
// R12 REDESIGN: the 2M random 64B gathers are per-CU miss-concurrency bound
// (~20-25 lines in flight/CU; R8/R10 pipelining and R11 L2-residency both
// failed to move it). This version ELIMINATES the random gather entirely:
//   norm -> bitmap(+zero bins) -> aq(compact anchor table, 256KB)
//   -> scatter records into (node_bucket x anchor_chunk) capacity bins
//   -> sweep: bucket's 1024 node rows staged in LDS (64KB, coalesced DMA),
//      anchor rows from L1-hot 256KB aq, e -> e_out[slot] (scatter write)
//   -> ovf (correctness net for bin overflow) -> anchor-major reduce.
// All remaining traffic is streaming, LDS, L1, or fire-and-forget writes.

// Normalize rows, quantize to biased int4 (nibble = clamp(rint(20*v),-7,7)+8).
// Row = 128 nibbles = 64B. Also zeroes d_out[0] (harness re-poisons out/ws).
__global__ __launch_bounds__(256) void norm_i4_kernel(const float* __restrict__ x,
                                                      unsigned short* __restrict__ xq,
                                                      float* __restrict__ out,
                                                      int N) {
    if (blockIdx.x == 0 && threadIdx.x == 0) out[0] = 0.0f;
    int lane = threadIdx.x & 31;
    int grp  = threadIdx.x >> 5;
    int row  = blockIdx.x * 8 + grp;
    if (row >= N) return;
    float4 v = *(const float4*)(x + (size_t)row * DIM + lane * 4);
    float s = v.x*v.x + v.y*v.y + v.z*v.z + v.w*v.w;
    s += __shfl_xor(s, 16); s += __shfl_xor(s, 8); s += __shfl_xor(s, 4);
    s += __shfl_xor(s, 2);  s += __shfl_xor(s, 1);
    float inv = rsqrtf(s) * QSCALE;
    int q0 = (int)fminf(fmaxf(rintf(v.x * inv), -7.0f), 7.0f) + 8;
    int q1 = (int)fminf(fmaxf(rintf(v.y * inv), -7.0f), 7.0f) + 8;
    int q2 = (int)fminf(fmaxf(rintf(v.z * inv), -7.0f), 7.0f) + 8;
    int q3 = (int)fminf(fmaxf(rintf(v.w * inv), -7.0f), 7.0f) + 8;
    xq[(size_t)row * 32 + lane] = (unsigned short)(q0 | (q1 << 4) | (q2 << 8) | (q3 << 12));
}

// Per-class node bitmaps via wave ballot. Also zeroes the bin counters +
// overflow counter (zbuf, zn) — harness poisons ws to 0xAA each replay.
__global__ __launch_bounds__(256) void bitmap_kernel(const int* __restrict__ y,
                                                     unsigned int* __restrict__ bitmap,
                                                     int words, int N,
                                                     unsigned int* __restrict__ zbuf, int zn) {
    int gtid = blockIdx.x * 256 + threadIdx.x;
    if (gtid < zn) zbuf[gtid] = 0u;

    int wave = threadIdx.x >> 6;
    int lane = threadIdx.x & 63;
    int base = blockIdx.x * 256 + wave * 64;
    if (base >= N) return;
    int n  = base + lane;
    int yv = (n < N) ? (y[n] & (NCLASS - 1)) : 255;
    int w0 = base >> 5;
#pragma unroll
    for (int c = 0; c < NCLASS; ++c) {
        unsigned long long m = __ballot(yv == c);
        if (lane == 0) {
            bitmap[(size_t)c * words + w0] = (unsigned int)m;
            if (w0 + 1 < words)
                bitmap[(size_t)c * words + w0 + 1] = (unsigned int)(m >> 32);
        }
    }
}

// Compact anchor feature table: aq[a] = xq[anchors[a]] (256KB, L1/L2-hot).
__global__ __launch_bounds__(256) void aq_kernel(const unsigned int* __restrict__ xq,
                                                 const int* __restrict__ anchors,
                                                 unsigned int* __restrict__ aq, int A16) {
    int t = blockIdx.x * 256 + threadIdx.x;
    if (t >= A16) return;
    int a = t >> 4, w = t & 15;
    aq[t] = xq[(size_t)anchors[a] * 16 + w];
}

// Counting scatter into capacity bins. bin = (node>>10)*512 + (anchor>>3).
// rec = (node&1023)<<21 | slot  (slot = a*512+s = linear index, <2^21).
__global__ __launch_bounds__(256) void scatter_kernel(const int* __restrict__ sampled,
                                                      unsigned int* __restrict__ cnt,
                                                      unsigned int* __restrict__ recs,
                                                      unsigned int* __restrict__ ovf_c,
                                                      unsigned long long* __restrict__ ovf,
                                                      int total) {
    int t = blockIdx.x * 256 + threadIdx.x;
    if (t >= total) return;
    int idx = sampled[t];
    int a   = t >> 9;
    int bin = (idx >> 10) * 512 + (a >> 3);
    unsigned pos = atomicAdd(cnt + bin, 1u);
    if (pos < CAP) {
        recs[(size_t)bin * CAP + pos] = ((unsigned)(idx & 1023) << 21) | (unsigned)t;
    } else {
        unsigned o = atomicAdd(ovf_c, 1u);
        if (o < OVF_MAX) ovf[o] = ((unsigned long long)(unsigned)idx << 32) | (unsigned)t;
    }
}

// Node-major sweep. Grid = NB*8 blocks, 512 threads. Block: bucket = bid>>3
// stages its 1024 node rows (64KB) into LDS via coalesced global_load_lds
// (wave-uniform LDS dest + lane*16, linear both sides), then 128 4-lane
// groups process 64 bins (2 groups/bin, parity-split). Node row from LDS,
// anchor row from aq (L1-hot: ~5 consecutive same-line reads per bin).
// dint = sum(na*ns) - 8*(Ta+Ts) + 8192 (exact integer sim*400).
__global__ __launch_bounds__(512) void sweep_kernel(const unsigned int* __restrict__ xq,
                                                    const unsigned int* __restrict__ aq,
                                                    const unsigned int* __restrict__ cnt,
                                                    const unsigned int* __restrict__ recs,
                                                    float* __restrict__ e_out, int N) {
    __shared__ __align__(16) char stage[65536];
    int bucket = blockIdx.x >> 3;
    int sub    = blockIdx.x & 7;
    int tid  = threadIdx.x;
    int wave = tid >> 6;
    int lane = tid & 63;

    // ---- stage bucket's node rows: 8 rounds x (8 waves x 1KB) = 64KB ----
    const char* xqb   = (const char*)xq;
    size_t base  = (size_t)bucket << 16;          // bucket*1024 rows * 64B
    size_t limit = (size_t)N << 6;
#pragma unroll
    for (int r = 0; r < 8; ++r) {
        int o = r * 8192 + wave * 1024 + lane * 16;
        size_t gb = base + (size_t)o;
        if (gb < limit) {
            __builtin_amdgcn_global_load_lds((const __attribute__((address_space(1))) void*)(xqb + gb),
                                             (__attribute__((address_space(3))) void*)(stage + r * 8192 + wave * 1024),
                                             16, 0, 0);
        }
    }
    asm volatile("s_waitcnt vmcnt(0)" ::: "memory");
    __syncthreads();

    // ---- process 64 bins, 2 4-lane groups per bin ----
    int g = tid >> 2, k = tid & 3;
    int binL = g & 63, par = g >> 6;
    int bin = bucket * 512 + sub * 64 + binL;
    int cn = (int)cnt[bin];
    if (cn > CAP) cn = CAP;
    const unsigned int* rb = recs + (size_t)bin * CAP;
    for (int it = par; it < cn; it += 2) {
        unsigned rec = rb[it];
        int slot = (int)(rec & 0x1FFFFFu);
        int lidx = (int)(rec >> 21);
        int a    = slot >> 9;
        const uint4 sr = *(const uint4*)(stage + (lidx << 6) + (k << 4));
        const uint4 an = *(const uint4*)(aq + (size_t)a * 16 + k * 4);
        unsigned bb = 0, t1 = 0, t2 = 0;
        bb = UDOT8(sr.x, an.x, bb);  t1 = UDOT8(sr.x, ONES, t1);  t2 = UDOT8(an.x, ONES, t2);
        bb = UDOT8(sr.y, an.y, bb);  t1 = UDOT8(sr.y, ONES, t1);  t2 = UDOT8(an.y, ONES, t2);
        bb = UDOT8(sr.z, an.z, bb);  t1 = UDOT8(sr.z, ONES, t1);  t2 = UDOT8(an.z, ONES, t2);
        bb = UDOT8(sr.w, an.w, bb);  t1 = UDOT8(sr.w, ONES, t1);  t2 = UDOT8(an.w, ONES, t2);
        int pc = (int)bb - 8 * (int)(t1 + t2);
        pc += __shfl_xor(pc, 1); pc += __shfl_xor(pc, 2);
        if (k == 0) e_out[slot] = exp2f((float)(pc + 8192) * C0);
    }
}

// Correctness net: process bin-overflow records (expected ~0) with direct
// global gathers. Single block.
__global__ __launch_bounds__(256) void ovf_kernel(const unsigned int* __restrict__ xq,
                                                  const unsigned int* __restrict__ aq,
                                                  const unsigned int* __restrict__ ovf_c,
                                                  const unsigned long long* __restrict__ ovf,
                                                  float* __restrict__ e_out) {
    unsigned n = *ovf_c;
    if (n > OVF_MAX) n = OVF_MAX;
    int g = threadIdx.x >> 2, k = threadIdx.x & 3;
    for (unsigned j = g; j < n; j += 64) {
        unsigned long long r = ovf[j];
        int idx  = (int)(r >> 32);
        int slot = (int)(r & 0xFFFFFFFFu);
        int a    = slot >> 9;
        const uint4 sr = *(const uint4*)(xq + (size_t)idx * 16 + k * 4);
        const uint4 an = *(const uint4*)(aq + (size_t)a * 16 + k * 4);
        unsigned bb = 0, t1 = 0, t2 = 0;
        bb = UDOT8(sr.x, an.x, bb);  t1 = UDOT8(sr.x, ONES, t1);  t2 = UDOT8(an.x, ONES, t2);
        bb = UDOT8(sr.y, an.y, bb);  t1 = UDOT8(sr.y, ONES, t1);  t2 = UDOT8(an.y, ONES, t2);
        bb = UDOT8(sr.z, an.z, bb);  t1 = UDOT8(sr.z, ONES, t1);  t2 = UDOT8(an.z, ONES, t2);
        bb = UDOT8(sr.w, an.w, bb);  t1 = UDOT8(sr.w, ONES, t1);  t2 = UDOT8(an.w, ONES, t2);
        int pc = (int)bb - 8 * (int)(t1 + t2);
        pc += __shfl_xor(pc, 1); pc += __shfl_xor(pc, 2);
        if (k == 0) e_out[slot] = exp2f((float)(pc + 8192) * C0);
    }
}

// Anchor-major reduce: coalesced e_out + sampled reads, bitmap pos test,
// block reduce, one atomic per anchor-block.
__global__ __launch_bounds__(256) void reduce_kernel(const float* __restrict__ e_out,
                                                     const int* __restrict__ y,
                                                     const int* __restrict__ anchors,
                                                     const int* __restrict__ sampled,
                                                     const unsigned int* __restrict__ bitmap,
                                                     int words,
                                                     float* __restrict__ out) {
    int a = blockIdx.x, t = threadIdx.x;
    int anchor = anchors[a];
    int ya     = y[anchor] & (NCLASS - 1);
    const unsigned int* bm = bitmap + (size_t)ya * words;
    float num = 0.0f, den = 0.0f, cntf = 0.0f;
#pragma unroll
    for (int h = 0; h < 2; ++h) {
        int slot = (a << 9) + t + h * 256;
        float e  = e_out[slot];
        int si   = sampled[slot];
        int pos  = (bm[si >> 5] >> (si & 31)) & 1;
        den += e;
        num += pos ? e : 0.0f;
        cntf += (float)pos;
    }
    num += __shfl_xor(num, 1);  den += __shfl_xor(den, 1);  cntf += __shfl_xor(cntf, 1);
    num += __shfl_xor(num, 2);  den += __shfl_xor(den, 2);  cntf += __shfl_xor(cntf, 2);
    num += __shfl_xor(num, 4);  den += __shfl_xor(den, 4);  cntf += __shfl_xor(cntf, 4);
    num += __shfl_xor(num, 8);  den += __shfl_xor(den, 8);  cntf += __shfl_xor(cntf, 8);
    num += __shfl_xor(num, 16); den += __shfl_xor(den, 16); cntf += __shfl_xor(cntf, 16);
    num += __shfl_xor(num, 32); den += __shfl_xor(den, 32); cntf += __shfl_xor(cntf, 32);
    __shared__ float sn[4], sd[4], sc[4];
    int wv = t >> 6;
    if ((t & 63) == 0) { sn[wv] = num; sd[wv] = den; sc[wv] = cntf; }
    __syncthreads();
    if (t == 0) {
        float tn = sn[0] + sn[1] + sn[2] + sn[3];
        float td = sd[0] + sd[1] + sd[2] + sd[3];
        float tc = sc[0] + sc[1] + sc[2] + sc[3];
        float loss = 0.0f;
        if (tc > 0.0f) loss = -__logf(tn / td) / tc;
        atomicAdd(out, loss);
    }
}

// ---------------- fp32 fallback (used only if ws too small / odd shape) -----

__global__ __launch_bounds__(256) void norm_kernel(const float* __restrict__ x,
                                                   float* __restrict__ inv_norm,
                                                   float* __restrict__ out,
                                                   int N) {
    if (blockIdx.x == 0 && threadIdx.x == 0) out[0] = 0.0f;
    int wave = threadIdx.x >> 6;
    int lane = threadIdx.x & 63;
    int row  = blockIdx.x * 4 + wave;
    if (row >= N) return;
    const float2 v = *(const float2*)(x + (size_t)row * DIM + lane * 2);
    float s = v.x * v.x + v.y * v.y;
    s += __shfl_xor(s, 32); s += __shfl_xor(s, 16); s += __shfl_xor(s, 8);
    s += __shfl_xor(s, 4);  s += __shfl_xor(s, 2);  s += __shfl_xor(s, 1);
    if (lane == 0) inv_norm[row] = rsqrtf(s);
}

__global__ __launch_bounds__(256) void loss_kernel(const float* __restrict__ x,
                                                   const int* __restrict__ y,
                                                   const int* __restrict__ anchors,
                                                   const int* __restrict__ sampled,
                                                   const float* __restrict__ inv_norm,
                                                   float* __restrict__ out,
                                                   int S) {
    int a     = blockIdx.x;
    int tid   = threadIdx.x;
    int lane  = tid & 31;
    int group = tid >> 5;

    int   anchor = anchors[a];
    int   ya     = y[anchor];
    float inv_a  = inv_norm[anchor];
    float4 av = *(const float4*)(x + (size_t)anchor * DIM + lane * 4);
    av.x *= inv_a; av.y *= inv_a; av.z *= inv_a; av.w *= inv_a;

    float num = 0.0f, den = 0.0f, cnt = 0.0f;
    const int* samp = sampled + (size_t)a * S;

#pragma unroll 4
    for (int s = group; s < S; s += 8) {
        int   sidx  = samp[s];
        float inv_s = inv_norm[sidx];
        int   ys    = y[sidx];
        const float4 sv = *(const float4*)(x + (size_t)sidx * DIM + lane * 4);
        float d = av.x * sv.x + av.y * sv.y + av.z * sv.z + av.w * sv.w;
        d += __shfl_xor(d, 16); d += __shfl_xor(d, 8); d += __shfl_xor(d, 4);
        d += __shfl_xor(d, 2);  d += __shfl_xor(d, 1);
        float e = __expf(d * inv_s * TEMP_INV);
        den += e;
        bool pos = (ys == ya);
        num += pos ? e : 0.0f;
        cnt += pos ? 1.0f : 0.0f;
    }

    __shared__ float s_num[8], s_den[8], s_cnt[8];
    if (lane == 0) { s_num[group] = num; s_den[group] = den; s_cnt[group] = cnt; }
    __syncthreads();
    if (tid == 0) {
        float tn = 0.0f, td = 0.0f, tc = 0.0f;
        for (int g = 0; g < 8; ++g) { tn += s_num[g]; td += s_den[g]; tc += s_cnt[g]; }
        float loss = 0.0f;
        if (tc > 0.0f) loss = -__logf(tn / td) / tc;
        atomicAdd(out, loss);
    }
}

extern "C" void kernel_launch(void* const* d_in, const int* in_sizes, int n_in,
                              void* d_out, int out_size, void* d_ws, size_t ws_size,
                              hipStream_t stream) {
    const float* x       = (const float*)d_in[0];
    const int*   y       = (const int*)d_in[1];
    const int*   anchors = (const int*)d_in[2];
    const int*   sampled = (const int*)d_in[3];

    int N = in_sizes[1];
    int A = in_sizes[2];
    int S = in_sizes[3] / A;

    float* out = (float*)d_out;
    int words = (N + 31) / 32;
    int NB    = (N + 1023) >> 10;       // node buckets of 1024 rows (64KB)
    int NBIN  = NB * 512;               // x 512 anchor-chunks (a>>3)

    size_t off_bm   = (size_t)N * 64;                        // xq: N x 64B
    size_t off_aq   = off_bm + (size_t)NCLASS * words * 4;   // bitmaps
    size_t off_cnt  = off_aq + (size_t)A * 64;               // aq: A x 64B
    size_t off_ovfc = off_cnt + (size_t)NBIN * 4;            // bin counters
    size_t off_ovf  = off_ovfc + 8;                          // ovf counter (+pad)
    size_t off_rec  = off_ovf + (size_t)OVF_MAX * 8;         // ovf list
    size_t off_e    = off_rec + (size_t)NBIN * CAP * 4;      // records
    size_t need     = off_e + (size_t)A * S * 4;             // e_out

    if (ws_size >= need && S == 512 && A <= 4096) {
        unsigned short*     xq4    = (unsigned short*)d_ws;
        const unsigned int* xqw    = (const unsigned int*)d_ws;
        unsigned int*       bitmap = (unsigned int*)((char*)d_ws + off_bm);
        unsigned int*       aq     = (unsigned int*)((char*)d_ws + off_aq);
        unsigned int*       cnt    = (unsigned int*)((char*)d_ws + off_cnt);
        unsigned int*       ovfc   = (unsigned int*)((char*)d_ws + off_ovfc);
        unsigned long long* ovf    = (unsigned long long*)((char*)d_ws + off_ovf);
        unsigned int*       recs   = (unsigned int*)((char*)d_ws + off_rec);
        float*              e_out  = (float*)((char*)d_ws + off_e);

        int total = A * S;
        norm_i4_kernel<<<(N + 7) / 8, 256, 0, stream>>>(x, xq4, out, N);
        bitmap_kernel<<<(N + 255) / 256, 256, 0, stream>>>(y, bitmap, words, N,
                                                           cnt, NBIN + 2);
        aq_kernel<<<(A * 16 + 255) / 256, 256, 0, stream>>>(xqw, anchors, aq, A * 16);
        scatter_kernel<<<(total + 255) / 256, 256, 0, stream>>>(sampled, cnt, recs,
                                                                ovfc, ovf, total);
        sweep_kernel<<<NB * 8, 512, 0, stream>>>(xqw, aq, cnt, recs, e_out, N);
        ovf_kernel<<<1, 256, 0, stream>>>(xqw, aq, ovfc, ovf, e_out);
        reduce_kernel<<<A, 256, 0, stream>>>(e_out, y, anchors, sampled, bitmap,
                                             words, out);
    } else {
        float* inv_norm = (float*)d_ws;
        norm_kernel<<<(N + 3) / 4, 256, 0, stream>>>(x, inv_norm, out, N);
        loss_kernel<<<A, 256, 0, stream>>>(x, y, anchors, sampled, inv_norm, out, S);
    }
}